// Round 9
// baseline (480.645 us; speedup 1.0000x reference)
//
#include <hip/hip_runtime.h>
#include <hip/hip_bf16.h>

#define B_ 32
#define S_ 4096
#define H_ 512
#define M_ (B_ * S_)   // 131072
#define L_ 2

typedef __bf16 bf16;
typedef bf16 bf16x8 __attribute__((ext_vector_type(8)));
typedef float floatx2 __attribute__((ext_vector_type(2)));
typedef float floatx4 __attribute__((ext_vector_type(4)));
typedef float floatx16 __attribute__((ext_vector_type(16)));

__device__ inline bf16 f2b(float f) { return (bf16)f; }

__device__ inline float fast_tanh(float x) {
    float xc = fminf(15.0f, fmaxf(-15.0f, x));
    float e = __expf(2.0f * xc);
    return (e - 1.0f) * __builtin_amdgcn_rcpf(e + 1.0f);
}

// ---------------- kernel 0: W (H,H) fp32 -> bf16 MFMA-fragment-major ----------------
// Fragment (nt, ks) = 32 W-rows x 16 k, stored as 64 lanes x 16B contiguous (1 KB):
// lane l holds W[nt*32 + (l&31)][ks*16 + (l>>5)*8 .. +8).
__global__ __launch_bounds__(256) void convert_Wfrag(const float* __restrict__ W,
                                                     bf16* __restrict__ Wf) {
    int gid  = blockIdx.x * 256 + threadIdx.x;   // 0..32767
    int lane = gid & 63;
    int ks   = (gid >> 6) & 31;
    int nt   = gid >> 11;                        // 0..15
    int row  = nt * 32 + (lane & 31);
    int col  = ks * 16 + (lane >> 5) * 8;
    const float* src = W + (size_t)row * H_ + col;
    floatx4 f0 = *(const floatx4*)src;
    floatx4 f1 = *(const floatx4*)(src + 4);
    bf16x8 p = { f2b(f0[0]), f2b(f0[1]), f2b(f0[2]), f2b(f0[3]),
                 f2b(f1[0]), f2b(f1[1]), f2b(f1[2]), f2b(f1[3]) };
    *(bf16x8*)(Wf + (size_t)gid * 8) = p;
}

// ---------------- kernel 1: fused scores + partial context (flash-style) --------
// 16 waves (1024 threads), wave w owns n in [w*32, w*32+32).
// OPERAND-SWAPPED MFMA (D[n][m], serial n-reduce, no shuffles) as in r8.
// TWO-PASS m-split: pass = mt processes one 32x32 acc tile (16 AGPR) so the
// combined register footprint fits 64/wave -> __launch_bounds__(1024,8) ->
// TWO phase-offset blocks per CU: one block's HBM stage overlaps the other's
// K-loop/epilogue. B-frags are re-read from L2 in pass 1 (same addrs, hot).
#define MT 64

__global__ __launch_bounds__(1024, 8) void scores_kernel(
    const float* __restrict__ outT,   // (M, 512)
    const bf16*  __restrict__ Wf,     // fragment-major W (512 KB)
    const float* __restrict__ bias,   // (512)
    const float* __restrict__ hidden, // (L, B, 512)
    const float* __restrict__ v,      // (512)
    float* __restrict__ scores,       // (M)
    float* __restrict__ pc,           // (M/MT, 512) partial context
    float* __restrict__ lmaxg,        // (M/MT)
    float* __restrict__ lsumg)        // (M/MT)
{
    __shared__ bf16 Alds[MT * 512];   // 64 KB, fragment-major
    __shared__ float bv[2 * H_];      // 4 KB: {bias+hlast, v} per n

    const int tid  = threadIdx.x;
    const int wave = tid >> 6;        // 0..15 == n-window owned by this wave
    const int lane = tid & 63;
    const int l31  = lane & 31;
    const int half = lane >> 5;       // 0..1

    const int m0    = blockIdx.x * MT;
    const int batch = m0 >> 12;       // m0 / S_
    const int koff  = (wave * 2) & 31;  // per-wave K rotation

    // per-lane Wf base: frag(nt, ks) at nt*16384 + ks*512 elements
    const bf16* wf = Wf + (size_t)wave * 16384 + lane * 8;

    // fill bv table (before the staging barrier; covered by it)
    if (tid < H_) {
        float bh = bias[tid] + hidden[(size_t)((L_ - 1) * B_ + batch) * H_ + tid];
        bv[tid * 2]     = bh;
        bv[tid * 2 + 1] = v[tid];
    }

    // ---- stage A: 64 rows x 512 fp32 -> bf16 fragment-major LDS.
    // A-frag (mt, ks): lane l holds A[mt*32 + (l&31)][ks*16 + (l>>5)*8 ..+8)
    // at slot = (l>>5)*32 + ((l&31) + ks)&31  (rotation kills write conflicts).
    {
        const floatx4* src = (const floatx4*)(outT + (size_t)m0 * H_);
        #pragma unroll
        for (int it = 0; it < 4; ++it) {
            int idx = it * 1024 + tid;    // 16B-block index: r = row, j = k-block
            int r   = idx >> 6;
            int j   = idx & 63;
            floatx4 f0 = __builtin_nontemporal_load(src + idx * 2);
            floatx4 f1 = __builtin_nontemporal_load(src + idx * 2 + 1);
            bf16x8 p = { f2b(f0[0]), f2b(f0[1]), f2b(f0[2]), f2b(f0[3]),
                         f2b(f1[0]), f2b(f1[1]), f2b(f1[2]), f2b(f1[3]) };
            int frag = (r >> 5) * 32 + (j >> 1);
            int slot = (j & 1) * 32 + ((r + (j >> 1)) & 31);
            *(bf16x8*)&Alds[frag * 512 + slot * 8] = p;
        }
    }
    __syncthreads();

    // ---- two m-passes; each pass: one 32x32 acc tile (16 AGPR) ----
    float p01[2];
    #pragma unroll
    for (int pass = 0; pass < 2; ++pass) {
        floatx16 acc = (floatx16)(0.0f);

        // B-ring depth 4
        bf16x8 bb[4];
        #pragma unroll
        for (int p = 0; p < 4; ++p)
            bb[p] = *(const bf16x8*)(wf + ((p + koff) & 31) * 512);

        // A ping-pong depth 2, this pass's mt only
        bf16x8 aa[2];
        {
            const int rot = (l31 + koff) & 31;
            aa[0] = *(const bf16x8*)
                &Alds[(pass * 32 + koff) * 512 + (half * 32 + rot) * 8];
        }

        #pragma unroll
        for (int ks = 0; ks < 32; ++ks) {
            const int bcur = ks & 3;
            const int ap   = ks & 1;
            // A-prefetch for ks+1
            if (ks < 31) {
                const int kk = (ks + 1 + koff) & 31;
                const int rot = (l31 + kk) & 31;
                aa[ap ^ 1] = *(const bf16x8*)
                    &Alds[(pass * 32 + kk) * 512 + (half * 32 + rot) * 8];
            }
            // SWAPPED operands: D[n][m]
            acc = __builtin_amdgcn_mfma_f32_32x32x16_bf16(bb[bcur], aa[ap], acc, 0, 0, 0);
            // B-prefetch for ks+4 into the slot JUST consumed
            if (ks < 28)
                bb[bcur] = *(const bf16x8*)(wf + ((ks + 4 + koff) & 31) * 512);
        }

        // per-lane serial n-reduction (no shuffles).
        // D[n][m]: m = pass*32 + (lane&31); n = wave*32 + (rg&3)+8*(rg>>2)+4*half.
        float p = 0.0f;
        #pragma unroll
        for (int rg = 0; rg < 16; ++rg) {
            const int nl = (rg & 3) + 8 * (rg >> 2) + 4 * half;
            floatx2 bvv = *(const floatx2*)&bv[(wave * 32 + nl) * 2];  // broadcast
            p += fast_tanh(acc[rg] + bvv.x) * bvv.y;
        }
        p += __shfl_xor(p, 32);   // merge the two k-halves (other 16 n's)
        p01[pass] = p;
    }

    __syncthreads();                 // done reading Alds; reuse as scratch
    float*   sred  = (float*)Alds;            // 16 waves x 64 rows = 4 KB
    float*   pbuf  = sred + 1024;             // 64 softmax numerators
    floatx4* pvred = (floatx4*)(pbuf + 64);   // 8 x 128 floatx4 = 16 KB

    if (lane < 32) {
        sred[wave * 64 + l31]      = p01[0];  // m = l31       (mt=0)
        sred[wave * 64 + 32 + l31] = p01[1];  // m = 32 + l31  (mt=1)
    }
    __syncthreads();

    // ---- flash-style local softmax numerators on the block's 64 rows ----
    if (tid < 64) {   // wave 0, full 64-lane wave
        float sc = 0.0f;
        #pragma unroll
        for (int w = 0; w < 16; ++w) sc += sred[w * 64 + tid];
        scores[m0 + tid] = sc;
        float mx = sc;
        #pragma unroll
        for (int off = 32; off >= 1; off >>= 1) mx = fmaxf(mx, __shfl_xor(mx, off));
        float p = __expf(sc - mx);
        pbuf[tid] = p;
        float sm = p;
        #pragma unroll
        for (int off = 32; off >= 1; off >>= 1) sm += __shfl_xor(sm, off);
        if (tid == 0) { lmaxg[blockIdx.x] = mx; lsumg[blockIdx.x] = sm; }
    }
    __syncthreads();

    // ---- partial context: pc[h] = sum_{s<64} p_s * out[m0+s][h] (fp32).
    // 8-way s-split across 1024 threads; NONTEMPORAL so the re-read does not
    // evict Wf from L2 (data is read-once, already L2/L3-hot from staging).
    {
        const int c4 = tid & 127;        // float4 column
        const int sg = tid >> 7;         // 0..7 -> 8-row group
        const floatx4* op = (const floatx4*)(outT + (size_t)(m0 + sg * 8) * H_) + c4;
        floatx4 a = (floatx4)(0.0f);
        #pragma unroll
        for (int j = 0; j < 8; ++j)
            a += pbuf[sg * 8 + j] * __builtin_nontemporal_load(op + (size_t)j * 128);
        pvred[sg * 128 + c4] = a;
    }
    __syncthreads();
    if (tid < 128) {
        floatx4 r = (floatx4)(0.0f);
        #pragma unroll
        for (int sg = 0; sg < 8; ++sg) r += pvred[sg * 128 + tid];
        *(floatx4*)&pc[(size_t)blockIdx.x * H_ + tid * 4] = r;
    }
}

// ---------------- kernel 2: softmax over S per batch (writes attn output) -------
__global__ __launch_bounds__(256) void softmax_kernel(const float* __restrict__ scores,
                                                      float* __restrict__ attn) {
    __shared__ float red[4];
    int b = blockIdx.x, tid = threadIdx.x;
    const float* row = scores + (size_t)b * S_;
    float vals[16];
    float mx = -3.4e38f;
    #pragma unroll
    for (int i = 0; i < 16; ++i) { vals[i] = row[i * 256 + tid]; mx = fmaxf(mx, vals[i]); }
    #pragma unroll
    for (int off = 32; off >= 1; off >>= 1) mx = fmaxf(mx, __shfl_xor(mx, off));
    if ((tid & 63) == 0) red[tid >> 6] = mx;
    __syncthreads();
    mx = fmaxf(fmaxf(red[0], red[1]), fmaxf(red[2], red[3]));
    __syncthreads();
    float sum = 0.f;
    #pragma unroll
    for (int i = 0; i < 16; ++i) { vals[i] = __expf(vals[i] - mx); sum += vals[i]; }
    #pragma unroll
    for (int off = 32; off >= 1; off >>= 1) sum += __shfl_xor(sum, off);
    if ((tid & 63) == 0) red[tid >> 6] = sum;
    __syncthreads();
    float inv = 1.0f / (red[0] + red[1] + red[2] + red[3]);
    #pragma unroll
    for (int i = 0; i < 16; ++i) attn[(size_t)b * S_ + i * 256 + tid] = vals[i] * inv;
}

// ---------------- kernel 3: combine 64 per-block partials -> ctx ----------------
// ctx[b][h] = ( sum_j exp(lmax_j - gmax) * pc[b*64+j][h] ) / gsum,
// gsum = sum_j exp(lmax_j - gmax) * lsum_j.   Reads only 4 MB total.
__global__ __launch_bounds__(256) void context_final(const float* __restrict__ pc,
                                                     const float* __restrict__ lmaxg,
                                                     const float* __restrict__ lsumg,
                                                     float* __restrict__ ctx) {
    __shared__ float e_sh[64];
    __shared__ float inv_sh;
    int b = blockIdx.x, tid = threadIdx.x;
    if (tid < 64) {    // wave 0: 64 per-block stats of this batch
        float lm = lmaxg[b * 64 + tid];
        float mx = lm;
        #pragma unroll
        for (int off = 32; off >= 1; off >>= 1) mx = fmaxf(mx, __shfl_xor(mx, off));
        float e = __expf(lm - mx);
        e_sh[tid] = e;
        float gs = e * lsumg[b * 64 + tid];
        #pragma unroll
        for (int off = 32; off >= 1; off >>= 1) gs += __shfl_xor(gs, off);
        if (tid == 0) inv_sh = 1.0f / gs;
    }
    __syncthreads();
    float inv = inv_sh;
    const floatx2* pp = (const floatx2*)(pc + (size_t)b * 64 * H_) + tid;
    floatx2 a = (floatx2)(0.0f);
    #pragma unroll 8
    for (int j = 0; j < 64; ++j) {
        floatx2 q = __builtin_nontemporal_load(pp + (size_t)j * 256);
        a += e_sh[j] * q;
    }
    floatx2 r = a * inv;
    *(floatx2*)&ctx[(size_t)b * H_ + tid * 2] = r;
}

extern "C" void kernel_launch(void* const* d_in, const int* in_sizes, int n_in,
                              void* d_out, int out_size, void* d_ws, size_t ws_size,
                              hipStream_t stream) {
    const float* outT   = (const float*)d_in[0];  // (B,S,H)
    const float* hidden = (const float*)d_in[1];  // (L,B,H)
    const float* W      = (const float*)d_in[2];  // (H,H)
    const float* bias   = (const float*)d_in[3];  // (H)
    const float* v      = (const float*)d_in[4];  // (H)

    float* ctx    = (float*)d_out;                // (B,H)
    float* attn   = (float*)d_out + B_ * H_;      // (B,S)

    const int NBLK = M_ / MT;                     // 2048
    float* scores = (float*)d_ws;                                   // 512 KB
    bf16*  Wf     = (bf16*)((char*)d_ws + (size_t)M_ * 4);          // 512 KB
    float* pc     = (float*)((char*)d_ws + (size_t)M_ * 4 + (size_t)H_ * H_ * 2); // 4 MB
    float* lmaxg  = pc + (size_t)NBLK * H_;                         // 8 KB
    float* lsumg  = lmaxg + NBLK;                                   // 8 KB

    convert_Wfrag<<<128, 256, 0, stream>>>(W, Wf);
    scores_kernel<<<NBLK, 1024, 0, stream>>>(outT, Wf, bias, hidden, v,
                                             scores, pc, lmaxg, lsumg);
    softmax_kernel<<<B_, 256, 0, stream>>>(scores, attn);
    context_final<<<B_, 256, 0, stream>>>(pc, lmaxg, lsumg, ctx);
}